// Round 1
// baseline (348.804 us; speedup 1.0000x reference)
//
#include <hip/hip_runtime.h>

#define NB 32
#define W 512
#define H 512
#define TX 64
#define TY 32
#define RW 74          // TX + 10
#define RH 42          // TY + 10
#define RSTRIDE 75     // +1 pad
#define BLOCK 256
#define C2f 0.0009f

// normalized gaussian(11, sigma=1.5)
#define G0 0.001028381f
#define G1 0.007598758f
#define G2 0.036000773f
#define G3 0.109360700f
#define G4 0.213005540f
#define G5 0.266011720f

__device__ __forceinline__ float sobel_mag(const float* s, int ly, int lx) {
    float a = s[(ly - 1) * RSTRIDE + (lx - 1)];
    float b = s[(ly - 1) * RSTRIDE + lx];
    float c = s[(ly - 1) * RSTRIDE + (lx + 1)];
    float d = s[ly * RSTRIDE + (lx - 1)];
    float f = s[ly * RSTRIDE + (lx + 1)];
    float g = s[(ly + 1) * RSTRIDE + (lx - 1)];
    float h = s[(ly + 1) * RSTRIDE + lx];
    float i = s[(ly + 1) * RSTRIDE + (lx + 1)];
    float gx = (c - a) + 2.f * (f - d) + (i - g);
    float gy = (a - g) + 2.f * (b - h) + (c - i);
    return fabsf(gx) + fabsf(gy);
}

__global__ __launch_bounds__(BLOCK) void fusion_main(
    const float* __restrict__ vis, const float* __restrict__ ir,
    const float* __restrict__ gen, double* __restrict__ sums) {
    __shared__ float s1[RH * RSTRIDE];  // gen
    __shared__ float s2[RH * RSTRIDE];  // ir
    __shared__ float s3[RH * RSTRIDE];  // vis
    __shared__ float sv[TY * RSTRIDE];  // vertical-conv scratch
    __shared__ float red[3][BLOCK / 64];

    const float gw[11] = {G0, G1, G2, G3, G4, G5, G4, G3, G2, G1, G0};

    const int tid = threadIdx.x;
    const size_t off = (size_t)blockIdx.z * (H * W);
    const int x0 = blockIdx.x * TX - 5;
    const int y0 = blockIdx.y * TY - 5;
    const float* pg = gen + off;
    const float* pi = ir + off;
    const float* pv = vis + off;

    // ---- stage halo region into LDS (zero-fill OOB, matches zero padding) ----
    for (int i = tid; i < RH * RW; i += BLOCK) {
        int ry = i / RW;
        int rx = i - ry * RW;
        int gx = x0 + rx, gy = y0 + ry;
        bool ok = ((unsigned)gx < W) && ((unsigned)gy < H);
        int gi = gy * W + gx;
        float a = 0.f, b = 0.f, c = 0.f;
        if (ok) { a = pg[gi]; b = pi[gi]; c = pv[gi]; }
        s1[ry * RSTRIDE + rx] = a;
        s2[ry * RSTRIDE + rx] = b;
        s3[ry * RSTRIDE + rx] = c;
    }
    __syncthreads();

    const int tx = tid & 63;
    const int tyb = tid >> 6;

    float sum_in = 0.f, sum_grad = 0.f, sum_ssim = 0.f;

    // ---- intensity L1 + sobel gradient L1 (halo 1 available) ----
    #pragma unroll
    for (int j = 0; j < 8; ++j) {
        int py = tyb + 4 * j;
        int ly = py + 5, lx = tx + 5;
        float gc = s1[ly * RSTRIDE + lx];
        float ic = s2[ly * RSTRIDE + lx];
        float vc = s3[ly * RSTRIDE + lx];
        sum_in += fabsf(gc - fmaxf(vc, ic));
        float gg = sobel_mag(s1, ly, lx);
        float gi2 = sobel_mag(s2, ly, lx);
        float gv = sobel_mag(s3, ly, lx);
        sum_grad += fabsf(gg - fmaxf(gv, gi2));
    }

    // ---- separable 11x11 gaussian convs: vertical into sv, horizontal into regs ----
#define VPASS(LOADEXPR)                                              \
    do {                                                             \
        for (int i = tid; i < TY * RW; i += BLOCK) {                 \
            int oy = i / RW;                                         \
            int rx = i - oy * RW;                                    \
            int b = oy * RSTRIDE + rx;                               \
            float acc = 0.f;                                         \
            _Pragma("unroll")                                        \
            for (int k = 0; k < 11; ++k) {                           \
                int idx = b + k * RSTRIDE;                           \
                acc = fmaf(gw[k], (LOADEXPR), acc);                  \
            }                                                        \
            sv[b] = acc;                                             \
        }                                                            \
    } while (0)

#define HPASS(dst)                                                   \
    do {                                                             \
        __syncthreads();                                             \
        _Pragma("unroll")                                            \
        for (int j = 0; j < 8; ++j) {                                \
            int py = tyb + 4 * j;                                    \
            int base = py * RSTRIDE + tx;                            \
            float acc = 0.f;                                         \
            _Pragma("unroll")                                        \
            for (int k = 0; k < 11; ++k)                             \
                acc = fmaf(gw[k], sv[base + k], acc);                \
            dst[j] = acc;                                            \
        }                                                            \
        __syncthreads();                                             \
    } while (0)

    float mu1[8], mu2[8], mu3[8], c11[8], c22[8], c33[8], c12[8], c13[8];
    VPASS(s1[idx]);            HPASS(mu1);
    VPASS(s2[idx]);            HPASS(mu2);
    VPASS(s3[idx]);            HPASS(mu3);
    VPASS(s1[idx] * s1[idx]);  HPASS(c11);
    VPASS(s2[idx] * s2[idx]);  HPASS(c22);
    VPASS(s3[idx] * s3[idx]);  HPASS(c33);
    VPASS(s1[idx] * s2[idx]);  HPASS(c12);
    VPASS(s1[idx] * s3[idx]);  HPASS(c13);

    // ---- ssim map (img1=gen, img2=ir, img3=vis) ----
    #pragma unroll
    for (int j = 0; j < 8; ++j) {
        float m1 = mu1[j], m2 = mu2[j], m3 = mu3[j];
        float sig1 = c11[j] - m1 * m1;
        float sig2 = c22[j] - m2 * m2;
        float sig3 = c33[j] - m3 * m3;
        float sg12 = c12[j] - m1 * m2;
        float sg13 = c13[j] - m1 * m3;
        float x2 = sqrtf(sig2);
        float x3 = sqrtf(sig3);
        float map12 = (2.f * sg12 + C2f) / (sig1 + sig2 + C2f);
        float map13 = (2.f * sg13 + C2f) / (sig1 + sig3 + C2f);
        // NaN-safe select: matches jnp.where(|x2| >= |x3|, map12, map13)
        sum_ssim += (x2 >= x3) ? map12 : map13;
    }

    // ---- block reduction -> global atomics ----
    #pragma unroll
    for (int o = 32; o > 0; o >>= 1) {
        sum_in   += __shfl_down(sum_in, o);
        sum_grad += __shfl_down(sum_grad, o);
        sum_ssim += __shfl_down(sum_ssim, o);
    }
    int lane = tid & 63, wv = tid >> 6;
    if (lane == 0) {
        red[0][wv] = sum_in;
        red[1][wv] = sum_grad;
        red[2][wv] = sum_ssim;
    }
    __syncthreads();
    if (tid == 0) {
        float a = 0.f, b = 0.f, c = 0.f;
        #pragma unroll
        for (int k = 0; k < BLOCK / 64; ++k) {
            a += red[0][k]; b += red[1][k]; c += red[2][k];
        }
        atomicAdd(&sums[0], (double)a);
        atomicAdd(&sums[1], (double)b);
        atomicAdd(&sums[2], (double)c);
    }
}

__global__ void finalize(const double* __restrict__ sums, float* __restrict__ out) {
    const double inv = 1.0 / ((double)NB * H * W);
    double loss_in = 1.5 * sums[0] * inv;
    double mean_grad = sums[1] * inv;
    double mean_ssim = sums[2] * inv;
    out[0] = (float)loss_in;
    out[1] = (float)(0.5 * (1.0 - mean_ssim) + mean_grad);
}

extern "C" void kernel_launch(void* const* d_in, const int* in_sizes, int n_in,
                              void* d_out, int out_size, void* d_ws, size_t ws_size,
                              hipStream_t stream) {
    const float* vis = (const float*)d_in[0];
    const float* ir  = (const float*)d_in[1];
    const float* gen = (const float*)d_in[2];
    float* out = (float*)d_out;
    double* sums = (double*)d_ws;

    hipMemsetAsync(d_ws, 0, 3 * sizeof(double), stream);
    dim3 grid(W / TX, H / TY, NB);
    fusion_main<<<grid, BLOCK, 0, stream>>>(vis, ir, gen, sums);
    finalize<<<1, 1, 0, stream>>>(sums, out);
}

// Round 2
// 293.084 us; speedup vs baseline: 1.1901x; 1.1901x over previous
//
#include <hip/hip_runtime.h>

#define NB 32
#define W 512
#define H 512
#define TX 64
#define TY 32
#define BLOCK 256
#define SP 81          // scratch pitch (dwords); 81%32=17, coprime -> conflict-free
#define C2f 0.0009f

// normalized gaussian(11, sigma=1.5)
#define GW0 0.001028381f
#define GW1 0.007598758f
#define GW2 0.036000773f
#define GW3 0.109360700f
#define GW4 0.213005540f
#define GW5 0.266011720f

__device__ __forceinline__ float gwv(int k) {
    const float g[11] = {GW0, GW1, GW2, GW3, GW4, GW5, GW4, GW3, GW2, GW1, GW0};
    return g[k];
}

template<bool GUARD>
__device__ __forceinline__ float ld(const float* __restrict__ p, int gy, int gx) {
    if (GUARD) {
        bool ok = ((unsigned)gx < W) && ((unsigned)gy < H);
        int cy = min(max(gy, 0), H - 1);
        int cx = min(max(gx, 0), W - 1);
        float v = p[cy * W + cx];
        return ok ? v : 0.f;
    }
    return p[gy * W + gx];
}

// vertical 11-tap gaussian for 4 quantities, register sliding window, direct
// global reads.  PHASE 0: {mu1(g), mu2(i), mu3(v), c11(g*g)}
//                PHASE 1: {c22(i*i), c33(v*v), c12(g*i), c13(g*v)}
template<bool GUARD, int PHASE>
__device__ __forceinline__ void vpass(
    const float* __restrict__ pg, const float* __restrict__ pi,
    const float* __restrict__ pv, float (&scr)[4][TY][SP],
    int x0, int y0, int tid) {
    for (int item = tid; item < 74 * 4; item += BLOCK) {
        int col = item % 74;
        int yc = item / 74;
        int gx = x0 - 5 + col;
        int ytop = y0 + yc * 8 - 5;
        float a[11], b[11], c[11];
        #pragma unroll
        for (int k = 0; k < 10; ++k) {
            int gy = ytop + k;
            a[k] = ld<GUARD>(pg, gy, gx);
            b[k] = ld<GUARD>(pi, gy, gx);
            c[k] = ld<GUARD>(pv, gy, gx);
        }
        #pragma unroll
        for (int r = 0; r < 8; ++r) {
            int gy = ytop + 10 + r;
            a[10] = ld<GUARD>(pg, gy, gx);
            b[10] = ld<GUARD>(pi, gy, gx);
            c[10] = ld<GUARD>(pv, gy, gx);
            float q0 = 0.f, q1 = 0.f, q2 = 0.f, q3 = 0.f;
            #pragma unroll
            for (int k = 0; k < 11; ++k) {
                float v1 = a[k], v2 = b[k], v3 = c[k], g = gwv(k);
                if (PHASE == 0) {
                    q0 = fmaf(g, v1, q0);
                    q1 = fmaf(g, v2, q1);
                    q2 = fmaf(g, v3, q2);
                    q3 = fmaf(g, v1 * v1, q3);
                } else {
                    q0 = fmaf(g, v2 * v2, q0);
                    q1 = fmaf(g, v3 * v3, q1);
                    q2 = fmaf(g, v1 * v2, q2);
                    q3 = fmaf(g, v1 * v3, q3);
                }
            }
            int rr = yc * 8 + r;
            scr[0][rr][col] = q0;
            scr[1][rr][col] = q1;
            scr[2][rr][col] = q2;
            scr[3][rr][col] = q3;
            #pragma unroll
            for (int k = 0; k < 10; ++k) {
                a[k] = a[k + 1]; b[k] = b[k + 1]; c[k] = c[k + 1];
            }
        }
    }
}

// horizontal 11-tap on scratch; thread owns (row, 8-output x-chunk), sliding
// window: 18 reads per quantity for 8 outputs.
__device__ __forceinline__ void hpass(const float (&scr)[4][TY][SP],
                                      float (&res)[4][8], int tid) {
    int r = tid & 31;
    int ch = tid >> 5;
    int xb = ch * 8;
    #pragma unroll
    for (int q = 0; q < 4; ++q) {
        float w[11];
        #pragma unroll
        for (int k = 0; k < 10; ++k) w[k] = scr[q][r][xb + k];
        #pragma unroll
        for (int j = 0; j < 8; ++j) {
            w[10] = scr[q][r][xb + 10 + j];
            float acc = 0.f;
            #pragma unroll
            for (int k = 0; k < 11; ++k) acc = fmaf(gwv(k), w[k], acc);
            res[q][j] = acc;
            #pragma unroll
            for (int k = 0; k < 10; ++k) w[k] = w[k + 1];
        }
    }
}

__device__ __forceinline__ float sob3(const float r0[3], const float r1[3],
                                      const float r2[3]) {
    float gx = (r0[2] - r0[0]) + 2.f * (r1[2] - r1[0]) + (r2[2] - r2[0]);
    float gy = (r0[0] - r2[0]) + 2.f * (r0[1] - r2[1]) + (r0[2] - r2[2]);
    return fabsf(gx) + fabsf(gy);
}

template<bool GUARD>
__device__ __forceinline__ void body(
    const float* __restrict__ pv, const float* __restrict__ pi,
    const float* __restrict__ pg, float (&scr)[4][TY][SP],
    float (&red)[3][4], int x0, int y0, double* __restrict__ sums) {
    const int tid = threadIdx.x;
    float sum_in = 0.f, sum_grad = 0.f, sum_ssim = 0.f;

    // ---- sobel + intensity: thread owns (col, 8-row chunk), sliding rows ----
    {
        int x = tid & 63;
        int yc = tid >> 6;
        int gx = x0 + x;
        int ybase = y0 + yc * 8;
        float g0[3], g1[3], g2[3], i0[3], i1[3], i2[3], v0[3], v1r[3], v2[3];
        #pragma unroll
        for (int c = 0; c < 3; ++c) {
            int gxx = gx - 1 + c;
            g0[c] = ld<GUARD>(pg, ybase - 1, gxx);
            i0[c] = ld<GUARD>(pi, ybase - 1, gxx);
            v0[c] = ld<GUARD>(pv, ybase - 1, gxx);
            g1[c] = ld<GUARD>(pg, ybase, gxx);
            i1[c] = ld<GUARD>(pi, ybase, gxx);
            v1r[c] = ld<GUARD>(pv, ybase, gxx);
        }
        #pragma unroll
        for (int j = 0; j < 8; ++j) {
            int gy = ybase + j + 1;
            #pragma unroll
            for (int c = 0; c < 3; ++c) {
                int gxx = gx - 1 + c;
                g2[c] = ld<GUARD>(pg, gy, gxx);
                i2[c] = ld<GUARD>(pi, gy, gxx);
                v2[c] = ld<GUARD>(pv, gy, gxx);
            }
            sum_in += fabsf(g1[1] - fmaxf(v1r[1], i1[1]));
            float sg = sob3(g0, g1, g2);
            float si = sob3(i0, i1, i2);
            float sv = sob3(v0, v1r, v2);
            sum_grad += fabsf(sg - fmaxf(sv, si));
            #pragma unroll
            for (int c = 0; c < 3; ++c) {
                g0[c] = g1[c]; g1[c] = g2[c];
                i0[c] = i1[c]; i1[c] = i2[c];
                v0[c] = v1r[c]; v1r[c] = v2[c];
            }
        }
    }

    // ---- SSIM: two 4-quantity separable conv phases ----
    float resA[4][8], resB[4][8];
    vpass<GUARD, 0>(pg, pi, pv, scr, x0, y0, tid);
    __syncthreads();
    hpass(scr, resA, tid);
    __syncthreads();
    vpass<GUARD, 1>(pg, pi, pv, scr, x0, y0, tid);
    __syncthreads();
    hpass(scr, resB, tid);

    #pragma unroll
    for (int j = 0; j < 8; ++j) {
        float m1 = resA[0][j], m2 = resA[1][j], m3 = resA[2][j];
        float sig1 = resA[3][j] - m1 * m1;
        float sig2 = resB[0][j] - m2 * m2;
        float sig3 = resB[1][j] - m3 * m3;
        float sg12 = resB[2][j] - m1 * m2;
        float sg13 = resB[3][j] - m1 * m3;
        float x2 = sqrtf(sig2);
        float x3 = sqrtf(sig3);
        float map12 = (2.f * sg12 + C2f) / (sig1 + sig2 + C2f);
        float map13 = (2.f * sg13 + C2f) / (sig1 + sig3 + C2f);
        // matches jnp.where(|x2| >= |x3|, map12, map13); NaN -> map13
        sum_ssim += (fabsf(x2) >= fabsf(x3)) ? map12 : map13;
    }

    // ---- reduce ----
    #pragma unroll
    for (int o = 32; o > 0; o >>= 1) {
        sum_in   += __shfl_down(sum_in, o);
        sum_grad += __shfl_down(sum_grad, o);
        sum_ssim += __shfl_down(sum_ssim, o);
    }
    int lane = tid & 63, wv = tid >> 6;
    if (lane == 0) { red[0][wv] = sum_in; red[1][wv] = sum_grad; red[2][wv] = sum_ssim; }
    __syncthreads();
    if (tid == 0) {
        float a = 0.f, b = 0.f, c = 0.f;
        #pragma unroll
        for (int k = 0; k < 4; ++k) { a += red[0][k]; b += red[1][k]; c += red[2][k]; }
        atomicAdd(&sums[0], (double)a);
        atomicAdd(&sums[1], (double)b);
        atomicAdd(&sums[2], (double)c);
    }
}

__global__ __launch_bounds__(BLOCK) void fusion_main(
    const float* __restrict__ vis, const float* __restrict__ ir,
    const float* __restrict__ gen, double* __restrict__ sums) {
    __shared__ float scr[4][TY][SP];
    __shared__ float red[3][4];
    const size_t off = (size_t)blockIdx.z * (H * W);
    const int x0 = blockIdx.x * TX;
    const int y0 = blockIdx.y * TY;
    const float* pv = vis + off;
    const float* pi = ir + off;
    const float* pg = gen + off;
    // interior blocks: every access in [0,512) on both axes -> unguarded loads
    bool interior = (blockIdx.x >= 1) && (blockIdx.x <= 6) &&
                    (blockIdx.y >= 1) && (blockIdx.y <= 14);
    if (interior) body<false>(pv, pi, pg, scr, red, x0, y0, sums);
    else          body<true>(pv, pi, pg, scr, red, x0, y0, sums);
}

__global__ void finalize(const double* __restrict__ sums, float* __restrict__ out) {
    const double inv = 1.0 / ((double)NB * H * W);
    out[0] = (float)(1.5 * sums[0] * inv);
    out[1] = (float)(0.5 * (1.0 - sums[2] * inv) + sums[1] * inv);
}

extern "C" void kernel_launch(void* const* d_in, const int* in_sizes, int n_in,
                              void* d_out, int out_size, void* d_ws, size_t ws_size,
                              hipStream_t stream) {
    const float* vis = (const float*)d_in[0];
    const float* ir  = (const float*)d_in[1];
    const float* gen = (const float*)d_in[2];
    float* out = (float*)d_out;
    double* sums = (double*)d_ws;

    hipMemsetAsync(d_ws, 0, 3 * sizeof(double), stream);
    dim3 grid(W / TX, H / TY, NB);
    fusion_main<<<grid, BLOCK, 0, stream>>>(vis, ir, gen, sums);
    finalize<<<1, 1, 0, stream>>>(sums, out);
}

// Round 3
// 292.309 us; speedup vs baseline: 1.1933x; 1.0027x over previous
//
#include <hip/hip_runtime.h>

#define NB 32
#define W 512
#define H 512
#define TX 64
#define TY 32
#define BLOCK 256
#define SP 77          // scratch pitch; 77%32=13 (odd, invertible) -> <=2-way banks (free)
#define C2f 0.0009f

// normalized gaussian(11, sigma=1.5)
#define GW0 0.001028381f
#define GW1 0.007598758f
#define GW2 0.036000773f
#define GW3 0.109360700f
#define GW4 0.213005540f
#define GW5 0.266011720f

__device__ __forceinline__ float gwv(int k) {
    const float g[11] = {GW0, GW1, GW2, GW3, GW4, GW5, GW4, GW3, GW2, GW1, GW0};
    return g[k];
}

template<bool GUARD>
__device__ __forceinline__ float ld(const float* __restrict__ p, int gy, int gx) {
    if (GUARD) {
        bool ok = ((unsigned)gx < W) && ((unsigned)gy < H);
        int cy = min(max(gy, 0), H - 1);
        int cx = min(max(gx, 0), W - 1);
        float v = p[cy * W + cx];
        return ok ? v : 0.f;
    }
    return p[gy * W + gx];
}

// vertical 11-tap gaussian for 4 quantities, register sliding window, direct
// global reads. 148 items (74 cols x 2 sixteen-row chunks) -> exactly one per
// thread: no second-round imbalance (was 296 items / 256 threads).
// PHASE 0: {mu1(g), mu2(i), mu3(v), c11(g*g)}
// PHASE 1: {c22(i*i), c33(v*v), c12(g*i), c13(g*v)}
template<bool GUARD, int PHASE>
__device__ __forceinline__ void vpass(
    const float* __restrict__ pg, const float* __restrict__ pi,
    const float* __restrict__ pv, float (&scr)[4][TY][SP],
    int x0, int y0, int tid) {
    if (tid < 148) {
        int yc = (tid >= 74) ? 1 : 0;
        int col = tid - 74 * yc;
        int gx = x0 - 5 + col;
        int ytop = y0 + yc * 16 - 5;
        float a[11], b[11], c[11];
        #pragma unroll
        for (int k = 0; k < 10; ++k) {
            int gy = ytop + k;
            a[k] = ld<GUARD>(pg, gy, gx);
            b[k] = ld<GUARD>(pi, gy, gx);
            c[k] = ld<GUARD>(pv, gy, gx);
        }
        #pragma unroll
        for (int r = 0; r < 16; ++r) {
            int gy = ytop + 10 + r;
            a[10] = ld<GUARD>(pg, gy, gx);
            b[10] = ld<GUARD>(pi, gy, gx);
            c[10] = ld<GUARD>(pv, gy, gx);
            float q0 = 0.f, q1 = 0.f, q2 = 0.f, q3 = 0.f;
            #pragma unroll
            for (int k = 0; k < 11; ++k) {
                float v1 = a[k], v2 = b[k], v3 = c[k], g = gwv(k);
                if (PHASE == 0) {
                    q0 = fmaf(g, v1, q0);
                    q1 = fmaf(g, v2, q1);
                    q2 = fmaf(g, v3, q2);
                    q3 = fmaf(g, v1 * v1, q3);
                } else {
                    q0 = fmaf(g, v2 * v2, q0);
                    q1 = fmaf(g, v3 * v3, q1);
                    q2 = fmaf(g, v1 * v2, q2);
                    q3 = fmaf(g, v1 * v3, q3);
                }
            }
            int rr = yc * 16 + r;
            scr[0][rr][col] = q0;
            scr[1][rr][col] = q1;
            scr[2][rr][col] = q2;
            scr[3][rr][col] = q3;
            #pragma unroll
            for (int k = 0; k < 10; ++k) {
                a[k] = a[k + 1]; b[k] = b[k + 1]; c[k] = c[k + 1];
            }
        }
    }
}

// horizontal 11-tap on scratch; thread owns (row, 8-output x-chunk), sliding
// window: 18 reads per quantity for 8 outputs.
__device__ __forceinline__ void hpass(const float (&scr)[4][TY][SP],
                                      float (&res)[4][8], int tid) {
    int r = tid & 31;
    int ch = tid >> 5;
    int xb = ch * 8;
    #pragma unroll
    for (int q = 0; q < 4; ++q) {
        float w[11];
        #pragma unroll
        for (int k = 0; k < 10; ++k) w[k] = scr[q][r][xb + k];
        #pragma unroll
        for (int j = 0; j < 8; ++j) {
            w[10] = scr[q][r][xb + 10 + j];
            float acc = 0.f;
            #pragma unroll
            for (int k = 0; k < 11; ++k) acc = fmaf(gwv(k), w[k], acc);
            res[q][j] = acc;
            #pragma unroll
            for (int k = 0; k < 10; ++k) w[k] = w[k + 1];
        }
    }
}

__device__ __forceinline__ float sob3(const float r0[3], const float r1[3],
                                      const float r2[3]) {
    float gx = (r0[2] - r0[0]) + 2.f * (r1[2] - r1[0]) + (r2[2] - r2[0]);
    float gy = (r0[0] - r2[0]) + 2.f * (r0[1] - r2[1]) + (r0[2] - r2[2]);
    return fabsf(gx) + fabsf(gy);
}

template<bool GUARD>
__device__ __forceinline__ void body(
    const float* __restrict__ pv, const float* __restrict__ pi,
    const float* __restrict__ pg, float (&scr)[4][TY][SP],
    float (&red)[3][4], int x0, int y0, double* __restrict__ sums) {
    const int tid = threadIdx.x;
    float sum_in = 0.f, sum_grad = 0.f, sum_ssim = 0.f;

    // ---- sobel + intensity: thread owns (col, 8-row chunk), sliding rows ----
    {
        int x = tid & 63;
        int yc = tid >> 6;
        int gx = x0 + x;
        int ybase = y0 + yc * 8;
        float g0[3], g1[3], g2[3], i0[3], i1[3], i2[3], v0[3], v1r[3], v2[3];
        #pragma unroll
        for (int c = 0; c < 3; ++c) {
            int gxx = gx - 1 + c;
            g0[c] = ld<GUARD>(pg, ybase - 1, gxx);
            i0[c] = ld<GUARD>(pi, ybase - 1, gxx);
            v0[c] = ld<GUARD>(pv, ybase - 1, gxx);
            g1[c] = ld<GUARD>(pg, ybase, gxx);
            i1[c] = ld<GUARD>(pi, ybase, gxx);
            v1r[c] = ld<GUARD>(pv, ybase, gxx);
        }
        #pragma unroll
        for (int j = 0; j < 8; ++j) {
            int gy = ybase + j + 1;
            #pragma unroll
            for (int c = 0; c < 3; ++c) {
                int gxx = gx - 1 + c;
                g2[c] = ld<GUARD>(pg, gy, gxx);
                i2[c] = ld<GUARD>(pi, gy, gxx);
                v2[c] = ld<GUARD>(pv, gy, gxx);
            }
            sum_in += fabsf(g1[1] - fmaxf(v1r[1], i1[1]));
            float sg = sob3(g0, g1, g2);
            float si = sob3(i0, i1, i2);
            float sv = sob3(v0, v1r, v2);
            sum_grad += fabsf(sg - fmaxf(sv, si));
            #pragma unroll
            for (int c = 0; c < 3; ++c) {
                g0[c] = g1[c]; g1[c] = g2[c];
                i0[c] = i1[c]; i1[c] = i2[c];
                v0[c] = v1r[c]; v1r[c] = v2[c];
            }
        }
    }

    // ---- SSIM: two 4-quantity separable conv phases ----
    float resA[4][8], resB[4][8];
    vpass<GUARD, 0>(pg, pi, pv, scr, x0, y0, tid);
    __syncthreads();
    hpass(scr, resA, tid);
    __syncthreads();
    vpass<GUARD, 1>(pg, pi, pv, scr, x0, y0, tid);
    __syncthreads();
    hpass(scr, resB, tid);

    #pragma unroll
    for (int j = 0; j < 8; ++j) {
        float m1 = resA[0][j], m2 = resA[1][j], m3 = resA[2][j];
        float sig1 = resA[3][j] - m1 * m1;
        float sig2 = resB[0][j] - m2 * m2;
        float sig3 = resB[1][j] - m3 * m3;
        float sg12 = resB[2][j] - m1 * m2;
        float sg13 = resB[3][j] - m1 * m3;
        float x2 = sqrtf(sig2);
        float x3 = sqrtf(sig3);
        float map12 = (2.f * sg12 + C2f) / (sig1 + sig2 + C2f);
        float map13 = (2.f * sg13 + C2f) / (sig1 + sig3 + C2f);
        // matches jnp.where(|x2| >= |x3|, map12, map13); NaN -> map13
        sum_ssim += (fabsf(x2) >= fabsf(x3)) ? map12 : map13;
    }

    // ---- reduce ----
    #pragma unroll
    for (int o = 32; o > 0; o >>= 1) {
        sum_in   += __shfl_down(sum_in, o);
        sum_grad += __shfl_down(sum_grad, o);
        sum_ssim += __shfl_down(sum_ssim, o);
    }
    int lane = tid & 63, wv = tid >> 6;
    if (lane == 0) { red[0][wv] = sum_in; red[1][wv] = sum_grad; red[2][wv] = sum_ssim; }
    __syncthreads();
    if (tid == 0) {
        float a = 0.f, b = 0.f, c = 0.f;
        #pragma unroll
        for (int k = 0; k < 4; ++k) { a += red[0][k]; b += red[1][k]; c += red[2][k]; }
        atomicAdd(&sums[0], (double)a);
        atomicAdd(&sums[1], (double)b);
        atomicAdd(&sums[2], (double)c);
    }
}

__global__ __launch_bounds__(BLOCK) void fusion_main(
    const float* __restrict__ vis, const float* __restrict__ ir,
    const float* __restrict__ gen, double* __restrict__ sums) {
    __shared__ float scr[4][TY][SP];   // 4*32*77*4 = 39424 B
    __shared__ float red[3][4];
    const size_t off = (size_t)blockIdx.z * (H * W);
    const int x0 = blockIdx.x * TX;
    const int y0 = blockIdx.y * TY;
    const float* pv = vis + off;
    const float* pi = ir + off;
    const float* pg = gen + off;
    // interior blocks: every access in [0,512) on both axes -> unguarded loads
    bool interior = (blockIdx.x >= 1) && (blockIdx.x <= 6) &&
                    (blockIdx.y >= 1) && (blockIdx.y <= 14);
    if (interior) body<false>(pv, pi, pg, scr, red, x0, y0, sums);
    else          body<true>(pv, pi, pg, scr, red, x0, y0, sums);
}

__global__ void finalize(const double* __restrict__ sums, float* __restrict__ out) {
    const double inv = 1.0 / ((double)NB * H * W);
    out[0] = (float)(1.5 * sums[0] * inv);
    out[1] = (float)(0.5 * (1.0 - sums[2] * inv) + sums[1] * inv);
}

extern "C" void kernel_launch(void* const* d_in, const int* in_sizes, int n_in,
                              void* d_out, int out_size, void* d_ws, size_t ws_size,
                              hipStream_t stream) {
    const float* vis = (const float*)d_in[0];
    const float* ir  = (const float*)d_in[1];
    const float* gen = (const float*)d_in[2];
    float* out = (float*)d_out;
    double* sums = (double*)d_ws;

    hipMemsetAsync(d_ws, 0, 3 * sizeof(double), stream);
    dim3 grid(W / TX, H / TY, NB);
    fusion_main<<<grid, BLOCK, 0, stream>>>(vis, ir, gen, sums);
    finalize<<<1, 1, 0, stream>>>(sums, out);
}